// Round 5
// baseline (278.348 us; speedup 1.0000x reference)
//
#include <hip/hip_runtime.h>
#include <hip/hip_bf16.h>

// DSMoE: B=4,S=2048 -> T=8192 tokens, D=512, H=1024, E=8 routed (top-2) + shared.
// bf16 MFMA token-gather MoE; shared expert folded in as expert 8.
// R5: BN=128 tiles in both stages (2x MFMA density, halved A re-reads),
//     fused single transpose kernel, Yc+combine (no output atomics).

#define Tn 8192
#define Dd 512
#define Hh 1024
#define NEx 9

typedef __attribute__((ext_vector_type(8))) short short8;
typedef __attribute__((ext_vector_type(4))) float f32x4;

#define AS1 __attribute__((address_space(1)))
#define AS3 __attribute__((address_space(3)))

#define OFF_XB    ((size_t)0)
#define OFF_W1T   (OFF_XB + (size_t)Tn * Dd * 2)
#define OFF_W3T   (OFF_W1T + (size_t)NEx * Hh * Dd * 2)
#define OFF_W2T   (OFF_W3T + (size_t)NEx * Hh * Dd * 2)
#define OFF_HBUF  (OFF_W2T + (size_t)NEx * Dd * Hh * 2)
#define OFF_TOK   (OFF_HBUF + (size_t)(3 * Tn) * Hh * 2)
#define OFF_SLOTP (OFF_TOK + (size_t)8 * Tn * 4)
#define OFF_PG    (OFF_SLOTP + (size_t)Tn * 2 * 4)
#define OFF_CNT   (OFF_PG + (size_t)Tn * 2 * 4)       // 8 counters, 128B apart
#define OFF_OFFS  (OFF_CNT + 1024)                    // off[9] then cntc[9]
#define OFF_YC    OFF_XB   // alias: Yc (25.2MB) over xb+w1t+w3t (27.3MB), dead by stage2

__device__ __forceinline__ ushort f2bf(float f) {
    unsigned int u = __float_as_uint(f);
    return (ushort)((u + 0x7fffu + ((u >> 16) & 1u)) >> 16);
}
__device__ __forceinline__ float bf2f(short s) {
    return __uint_as_float(((unsigned int)(unsigned short)s) << 16);
}

// ---------- fused transpose: all 27 weight slices in one launch ----------
// fam 0: w1 [D][H]->[H][D], fam 1: w3, fam 2: w2 [H][D]->[D][H]; slice 8 = shared.
__global__ __launch_bounds__(256) void trans_kernel(
        const float* __restrict__ w1, const float* __restrict__ sw1,
        const float* __restrict__ w3, const float* __restrict__ sw3,
        const float* __restrict__ w2, const float* __restrict__ sw2,
        ushort* __restrict__ w1t, ushort* __restrict__ w3t, ushort* __restrict__ w2t) {
    __shared__ float tile[32][33];
    int z = blockIdx.z;
    int fam = z / 9, sl = z - fam * 9;
    const float* src; ushort* dst;
    int R, C, r0, c0;
    if (fam == 0)      { src = (sl < 8) ? w1 + (size_t)sl * Dd * Hh : sw1; dst = w1t + (size_t)sl * Dd * Hh; R = Dd; C = Hh; c0 = blockIdx.x * 32; r0 = blockIdx.y * 32; }
    else if (fam == 1) { src = (sl < 8) ? w3 + (size_t)sl * Dd * Hh : sw3; dst = w3t + (size_t)sl * Dd * Hh; R = Dd; C = Hh; c0 = blockIdx.x * 32; r0 = blockIdx.y * 32; }
    else               { src = (sl < 8) ? w2 + (size_t)sl * Dd * Hh : sw2; dst = w2t + (size_t)sl * Dd * Hh; R = Hh; C = Dd; r0 = blockIdx.x * 32; c0 = blockIdx.y * 32; }
    int tx = threadIdx.x & 31, ty = threadIdx.x >> 5;
#pragma unroll
    for (int k = 0; k < 4; ++k)
        tile[ty + 8 * k][tx] = src[(size_t)(r0 + ty + 8 * k) * C + c0 + tx];
    __syncthreads();
#pragma unroll
    for (int k = 0; k < 4; ++k)
        dst[(size_t)(c0 + ty + 8 * k) * R + r0 + tx] = f2bf(tile[tx][ty + 8 * k]);
}

// ---------- router: 32 tokens/block, LDS-aggregated atomics; also emits xb + slot map ----------
__global__ __launch_bounds__(256) void router_kernel(const float* __restrict__ x,
                                                     const float* __restrict__ gw,
                                                     const float* __restrict__ bias,
                                                     int* __restrict__ cnt,     // padded: cnt[e*32]
                                                     int* __restrict__ tok,
                                                     int* __restrict__ slotp,
                                                     float* __restrict__ pg,
                                                     ushort* __restrict__ xb) {
    __shared__ int le[64];
    __shared__ float lg[64];
    __shared__ int lpos[64];
    __shared__ int lcnt[8];
    __shared__ int gbase[8];
    int tid = threadIdx.x, lane = tid & 63, wave = tid >> 6;
    if (tid < 8) lcnt[tid] = 0;
    __syncthreads();
    int t0 = blockIdx.x * 32 + wave * 8;
    for (int it = 0; it < 8; ++it) {
        int t = t0 + it;
        const float4* xr = (const float4*)(x + (size_t)t * Dd);
        float4 xa = xr[lane * 2], xc = xr[lane * 2 + 1];
        ushort4 o1, o2;
        o1.x = f2bf(xa.x); o1.y = f2bf(xa.y); o1.z = f2bf(xa.z); o1.w = f2bf(xa.w);
        o2.x = f2bf(xc.x); o2.y = f2bf(xc.y); o2.z = f2bf(xc.z); o2.w = f2bf(xc.w);
        *(ushort4*)(xb + (size_t)t * Dd + lane * 8) = o1;
        *(ushort4*)(xb + (size_t)t * Dd + lane * 8 + 4) = o2;
        float sc[8];
#pragma unroll
        for (int e = 0; e < 8; ++e) {
            const float4* gr = (const float4*)(gw + (size_t)e * Dd);
            float4 ga = gr[lane * 2], gc = gr[lane * 2 + 1];
            float s = xa.x * ga.x + xa.y * ga.y + xa.z * ga.z + xa.w * ga.w
                    + xc.x * gc.x + xc.y * gc.y + xc.z * gc.z + xc.w * gc.w;
#pragma unroll
            for (int o = 32; o > 0; o >>= 1) s += __shfl_xor(s, o);
            sc[e] = s;
        }
        if (lane == 0) {
            float b0 = -1e30f; int i0 = 0;
#pragma unroll
            for (int e = 0; e < 8; ++e) { float bv = sc[e] + bias[e]; if (bv > b0) { b0 = bv; i0 = e; } }
            float b1v = -1e30f; int i1 = (i0 == 0) ? 1 : 0;
#pragma unroll
            for (int e = 0; e < 8; ++e) if (e != i0) { float bv = sc[e] + bias[e]; if (bv > b1v) { b1v = bv; i1 = e; } }
            float v0 = -1e30f; int k0i = 0;
#pragma unroll
            for (int e = 0; e < 8; ++e) if (sc[e] > v0) { v0 = sc[e]; k0i = e; }
            float v1 = -1e30f;
#pragma unroll
            for (int e = 0; e < 8; ++e) if (e != k0i && sc[e] > v1) v1 = sc[e];
            float p0 = 1.f / (1.f + __expf(-v0));
            float p1 = 1.f / (1.f + __expf(-v1));
            float inv = 1.f / (p0 + p1);
            int ai = (wave * 8 + it) * 2;
            le[ai] = i0;     lg[ai] = p0 * inv;
            le[ai + 1] = i1; lg[ai + 1] = p1 * inv;
        }
    }
    __syncthreads();
    if (tid < 64) lpos[tid] = atomicAdd(&lcnt[le[tid]], 1);
    __syncthreads();
    if (tid < 8) gbase[tid] = atomicAdd(&cnt[tid * 32], lcnt[tid]);
    __syncthreads();
    if (tid < 64) {
        int e = le[tid];
        int dst = gbase[e] + lpos[tid];
        int t = blockIdx.x * 32 + (tid >> 1);
        tok[(size_t)e * Tn + dst] = t;
        slotp[t * 2 + (tid & 1)] = (e << 16) | dst;
        pg[t * 2 + (tid & 1)] = lg[tid];
    }
}

// ---------- scan ----------
__global__ void scan_kernel(const int* cnt, int* off, int* cntc) {
    if (threadIdx.x == 0 && blockIdx.x == 0) {
        int s = 0;
        for (int e = 0; e < 8; ++e) { int c = cnt[e * 32]; cntc[e] = c; off[e] = s; s += c; }
        off[8] = s;
        cntc[8] = Tn;
    }
}

// ---------- stage1: H = silu(Xg@W1) * (Xg@W3), tile 128x128(+128), BK=64 ----------
// grid (64, 8, 9): x=row-block (pins XCD: flat%8 = x%8), y=n-block(128 cols).
__global__ __launch_bounds__(256, 2) void stage1_kernel(
        const ushort* __restrict__ xb, const ushort* __restrict__ w1t,
        const ushort* __restrict__ w3t, const int* __restrict__ tok,
        const int* __restrict__ cntc, const int* __restrict__ off,
        ushort* __restrict__ Hbuf) {
    int e = blockIdx.z;
    int cn = cntc[e];
    int m0 = blockIdx.x * 128;
    if (m0 >= cn) return;
    int n0 = blockIdx.y * 128;
    const ushort* w1e = w1t + (size_t)e * Hh * Dd;
    const ushort* w3e = w3t + (size_t)e * Hh * Dd;

    __shared__ ushort As[128 * 64];
    __shared__ ushort B1s[128 * 64];
    __shared__ ushort B3s[128 * 64];
    __shared__ int toks[128];

    int tid = threadIdx.x;
    if (tid < 128) {
        int slot = m0 + tid;
        int sl = slot < cn ? slot : cn - 1;
        toks[tid] = (e == 8) ? sl : tok[(size_t)e * Tn + sl];
    }
    __syncthreads();

    int lane = tid & 63, wave = tid >> 6;
    int wm = (wave & 1) * 64, wn = (wave >> 1) * 64;
    int col15 = lane & 15, quad = lane >> 4;
    int lr = lane >> 3;                 // row within 8-row chunk (staging)
    int lcx = ((lane & 7) ^ lr) * 8;    // swizzled logical k-offset (shorts)

    f32x4 acc1[4][4], acc3[4][4];
#pragma unroll
    for (int a = 0; a < 4; ++a)
#pragma unroll
        for (int b = 0; b < 4; ++b) {
            acc1[a][b] = (f32x4){0.f, 0.f, 0.f, 0.f};
            acc3[a][b] = (f32x4){0.f, 0.f, 0.f, 0.f};
        }

    for (int kb = 0; kb < Dd; kb += 64) {
#pragma unroll
        for (int i = 0; i < 4; ++i) {
            int cid = wave * 4 + i;
            const ushort* g = xb + (size_t)toks[cid * 8 + lr] * Dd + kb + lcx;
            __builtin_amdgcn_global_load_lds((const AS1 void*)g, (AS3 void*)(As + cid * 512), 16, 0, 0);
        }
#pragma unroll
        for (int i = 0; i < 4; ++i) {
            int cid = wave * 4 + i;
            int r = n0 + cid * 8 + lr;
            const ushort* g1 = w1e + (size_t)r * Dd + kb + lcx;
            const ushort* g3 = w3e + (size_t)r * Dd + kb + lcx;
            __builtin_amdgcn_global_load_lds((const AS1 void*)g1, (AS3 void*)(B1s + cid * 512), 16, 0, 0);
            __builtin_amdgcn_global_load_lds((const AS1 void*)g3, (AS3 void*)(B3s + cid * 512), 16, 0, 0);
        }
        __syncthreads();
#pragma unroll
        for (int ks = 0; ks < 2; ++ks) {
            int px = ((ks * 4 + quad) ^ (col15 & 7)) * 8;   // swizzled k-offset (shorts)
            short8 a[4], b1[4], b3[4];
#pragma unroll
            for (int mi = 0; mi < 4; ++mi)
                a[mi] = *(const short8*)&As[(wm + mi * 16 + col15) * 64 + px];
#pragma unroll
            for (int ni = 0; ni < 4; ++ni) {
                b1[ni] = *(const short8*)&B1s[(wn + ni * 16 + col15) * 64 + px];
                b3[ni] = *(const short8*)&B3s[(wn + ni * 16 + col15) * 64 + px];
            }
#pragma unroll
            for (int mi = 0; mi < 4; ++mi)
#pragma unroll
                for (int ni = 0; ni < 4; ++ni) {
                    acc1[mi][ni] = __builtin_amdgcn_mfma_f32_16x16x32_bf16(a[mi], b1[ni], acc1[mi][ni], 0, 0, 0);
                    acc3[mi][ni] = __builtin_amdgcn_mfma_f32_16x16x32_bf16(a[mi], b3[ni], acc3[mi][ni], 0, 0, 0);
                }
        }
        __syncthreads();
    }

    int oe = off[e];
#pragma unroll
    for (int mi = 0; mi < 4; ++mi)
#pragma unroll
        for (int r = 0; r < 4; ++r) {
            int slot = m0 + wm + mi * 16 + quad * 4 + r;   // C layout: row = quad*4+reg
            if (slot < cn) {
                size_t rowb = (size_t)(oe + slot) * Hh;
#pragma unroll
                for (int ni = 0; ni < 4; ++ni) {
                    float h1 = acc1[mi][ni][r], h3 = acc3[mi][ni][r];
                    float s = h1 / (1.f + __expf(-h1));
                    Hbuf[rowb + n0 + wn + ni * 16 + col15] = f2bf(s * h3);
                }
            }
        }
}

// ---------- stage2: Yc[slot] = Hrow @ W2, tile 128x128, BK=64 ----------
// grid (64, 4, 9): x=row-block (pins XCD), y=n-block(128 cols).
__global__ __launch_bounds__(256, 3) void stage2_kernel(
        const ushort* __restrict__ Hbuf, const ushort* __restrict__ w2t,
        const int* __restrict__ cntc, const int* __restrict__ off,
        ushort* __restrict__ Yc) {
    int e = blockIdx.z;
    int cn = cntc[e];
    int m0 = blockIdx.x * 128;
    if (m0 >= cn) return;
    int n0 = blockIdx.y * 128;
    int oe = off[e];
    const ushort* w2e = w2t + (size_t)e * Dd * Hh;

    __shared__ ushort As[128 * 64];
    __shared__ ushort Bs[128 * 64];

    int tid = threadIdx.x;
    int lane = tid & 63, wave = tid >> 6;
    int wm = (wave & 1) * 64, wn = (wave >> 1) * 64;
    int col15 = lane & 15, quad = lane >> 4;
    int lr = lane >> 3;
    int lcx = ((lane & 7) ^ lr) * 8;

    f32x4 acc[4][4];
#pragma unroll
    for (int a = 0; a < 4; ++a)
#pragma unroll
        for (int b = 0; b < 4; ++b) acc[a][b] = (f32x4){0.f, 0.f, 0.f, 0.f};

    for (int kb = 0; kb < Hh; kb += 64) {
#pragma unroll
        for (int i = 0; i < 4; ++i) {
            int cid = wave * 4 + i;
            const ushort* g = Hbuf + (size_t)(oe + m0 + cid * 8 + lr) * Hh + kb + lcx;
            __builtin_amdgcn_global_load_lds((const AS1 void*)g, (AS3 void*)(As + cid * 512), 16, 0, 0);
        }
#pragma unroll
        for (int i = 0; i < 4; ++i) {
            int cid = wave * 4 + i;
            const ushort* g = w2e + (size_t)(n0 + cid * 8 + lr) * Hh + kb + lcx;
            __builtin_amdgcn_global_load_lds((const AS1 void*)g, (AS3 void*)(Bs + cid * 512), 16, 0, 0);
        }
        __syncthreads();
#pragma unroll
        for (int ks = 0; ks < 2; ++ks) {
            int px = ((ks * 4 + quad) ^ (col15 & 7)) * 8;
            short8 a[4], b[4];
#pragma unroll
            for (int mi = 0; mi < 4; ++mi)
                a[mi] = *(const short8*)&As[(wm + mi * 16 + col15) * 64 + px];
#pragma unroll
            for (int ni = 0; ni < 4; ++ni)
                b[ni] = *(const short8*)&Bs[(wn + ni * 16 + col15) * 64 + px];
#pragma unroll
            for (int mi = 0; mi < 4; ++mi)
#pragma unroll
                for (int ni = 0; ni < 4; ++ni)
                    acc[mi][ni] = __builtin_amdgcn_mfma_f32_16x16x32_bf16(a[mi], b[ni], acc[mi][ni], 0, 0, 0);
        }
        __syncthreads();
    }

#pragma unroll
    for (int mi = 0; mi < 4; ++mi)
#pragma unroll
        for (int r = 0; r < 4; ++r) {
            int slot = m0 + wm + mi * 16 + quad * 4 + r;
            if (slot < cn) {
                size_t rowb = (size_t)(oe + slot) * Dd;
#pragma unroll
                for (int ni = 0; ni < 4; ++ni)
                    Yc[rowb + n0 + wn + ni * 16 + col15] = f2bf(acc[mi][ni][r]);
            }
        }
}

// ---------- combine: out[t] = g0*Yc[s0] + g1*Yc[s1] + Yc[shared+t] ----------
__global__ __launch_bounds__(256) void combine_kernel(const ushort* __restrict__ Yc,
        const int* __restrict__ slotp, const float* __restrict__ pg,
        const int* __restrict__ off, float* __restrict__ out) {
    int g = blockIdx.x * 256 + threadIdx.x;
    int t = g >> 6;
    int c = (g & 63) * 8;
    int p0 = slotp[t * 2], p1 = slotp[t * 2 + 1];
    float g0 = pg[t * 2], g1 = pg[t * 2 + 1];
    int s0 = off[p0 >> 16] + (p0 & 0xffff);
    int s1 = off[p1 >> 16] + (p1 & 0xffff);
    int s2 = off[8] + t;
    short8 a = *(const short8*)(Yc + (size_t)s0 * Dd + c);
    short8 b = *(const short8*)(Yc + (size_t)s1 * Dd + c);
    short8 d = *(const short8*)(Yc + (size_t)s2 * Dd + c);
    float o[8];
#pragma unroll
    for (int i = 0; i < 8; ++i)
        o[i] = g0 * bf2f(a[i]) + g1 * bf2f(b[i]) + bf2f(d[i]);
    float* dst = out + (size_t)t * Dd + c;
    *(float4*)dst = (float4){o[0], o[1], o[2], o[3]};
    *(float4*)(dst + 4) = (float4){o[4], o[5], o[6], o[7]};
}

extern "C" void kernel_launch(void* const* d_in, const int* in_sizes, int n_in,
                              void* d_out, int out_size, void* d_ws, size_t ws_size,
                              hipStream_t stream) {
    (void)in_sizes; (void)n_in; (void)out_size; (void)ws_size;
    const float* x    = (const float*)d_in[0];
    const float* gw   = (const float*)d_in[1];
    const float* bias = (const float*)d_in[2];
    const float* w1   = (const float*)d_in[3];
    const float* w3   = (const float*)d_in[4];
    const float* w2   = (const float*)d_in[5];
    const float* sw1  = (const float*)d_in[6];
    const float* sw3  = (const float*)d_in[7];
    const float* sw2  = (const float*)d_in[8];
    float* out = (float*)d_out;

    char* ws = (char*)d_ws;
    ushort* xb    = (ushort*)(ws + OFF_XB);
    ushort* w1t   = (ushort*)(ws + OFF_W1T);
    ushort* w3t   = (ushort*)(ws + OFF_W3T);
    ushort* w2t   = (ushort*)(ws + OFF_W2T);
    ushort* Hbuf  = (ushort*)(ws + OFF_HBUF);
    ushort* Yc    = (ushort*)(ws + OFF_YC);
    int*    tok   = (int*)(ws + OFF_TOK);
    int*    slotp = (int*)(ws + OFF_SLOTP);
    float*  pg    = (float*)(ws + OFF_PG);
    int*    cnt   = (int*)(ws + OFF_CNT);
    int*    off   = (int*)(ws + OFF_OFFS);
    int*    cntc  = off + 16;

    hipMemsetAsync(cnt, 0, 1024, stream);

    trans_kernel<<<dim3(32, 16, 27), 256, 0, stream>>>(w1, sw1, w3, sw3, w2, sw2, w1t, w3t, w2t);
    router_kernel<<<256, 256, 0, stream>>>(x, gw, bias, cnt, tok, slotp, pg, xb);
    scan_kernel<<<1, 64, 0, stream>>>(cnt, off, cntc);

    stage1_kernel<<<dim3(64, Hh / 128, NEx), 256, 0, stream>>>(xb, w1t, w3t, tok, cntc, off, Hbuf);
    stage2_kernel<<<dim3(64, Dd / 128, NEx), 256, 0, stream>>>(Hbuf, w2t, cntc, off, Yc);
    combine_kernel<<<2048, 256, 0, stream>>>(Yc, slotp, pg, off, out);
}

// Round 6
// 262.981 us; speedup vs baseline: 1.0584x; 1.0584x over previous
//
#include <hip/hip_runtime.h>
#include <hip/hip_bf16.h>

// DSMoE: B=4,S=2048 -> T=8192 tokens, D=512, H=1024, E=8 routed (top-2) + shared.
// bf16 MFMA token-gather MoE; shared expert folded in as expert 8.
// R6: W1/W3 interleaved (16-col blocks) into one w13t -> stage1 is a plain
//     128x128 GEMM with a SINGLE acc[4][4] (64 AGPR) and in-lane silu pairing.

#define Tn 8192
#define Dd 512
#define Hh 1024
#define NEx 9

typedef __attribute__((ext_vector_type(8))) short short8;
typedef __attribute__((ext_vector_type(4))) float f32x4;

#define AS1 __attribute__((address_space(1)))
#define AS3 __attribute__((address_space(3)))

#define OFF_XB    ((size_t)0)
#define OFF_W13T  (OFF_XB + (size_t)Tn * Dd * 2)
#define OFF_W2T   (OFF_W13T + (size_t)NEx * 2 * Hh * Dd * 2)
#define OFF_HBUF  (OFF_W2T + (size_t)NEx * Dd * Hh * 2)
#define OFF_TOK   (OFF_HBUF + (size_t)(3 * Tn) * Hh * 2)
#define OFF_SLOTP (OFF_TOK + (size_t)8 * Tn * 4)
#define OFF_PG    (OFF_SLOTP + (size_t)Tn * 2 * 4)
#define OFF_CNT   (OFF_PG + (size_t)Tn * 2 * 4)       // 8 counters, 128B apart
#define OFF_OFFS  (OFF_CNT + 1024)                    // off[9] then cntc[9]
#define OFF_YC    OFF_XB   // alias: Yc (25.2MB) over xb+w13t (26.9MB), dead by stage2

__device__ __forceinline__ ushort f2bf(float f) {
    unsigned int u = __float_as_uint(f);
    return (ushort)((u + 0x7fffu + ((u >> 16) & 1u)) >> 16);
}
__device__ __forceinline__ float bf2f(short s) {
    return __uint_as_float(((unsigned int)(unsigned short)s) << 16);
}

// ---------- fused transpose: 27 slices; fam 0/1 interleave into w13t ----------
// fam 0: w1, fam 1: w3 -> w13t rows n = ((h>>4)*2+fam)*16 + (h&15); fam 2: w2 plain.
__global__ __launch_bounds__(256) void trans_kernel(
        const float* __restrict__ w1, const float* __restrict__ sw1,
        const float* __restrict__ w3, const float* __restrict__ sw3,
        const float* __restrict__ w2, const float* __restrict__ sw2,
        ushort* __restrict__ w13t, ushort* __restrict__ w2t) {
    __shared__ float tile[32][33];
    int z = blockIdx.z;
    int fam = z / 9, sl = z - fam * 9;
    int tx = threadIdx.x & 31, ty = threadIdx.x >> 5;
    if (fam < 2) {
        const float* base = (fam == 0) ? ((sl < 8) ? w1 + (size_t)sl * Dd * Hh : sw1)
                                       : ((sl < 8) ? w3 + (size_t)sl * Dd * Hh : sw3);
        ushort* dst = w13t + (size_t)sl * 2 * Hh * Dd;
        int c0 = blockIdx.x * 32, r0 = blockIdx.y * 32;   // c: hidden, r: dim
#pragma unroll
        for (int k = 0; k < 4; ++k)
            tile[ty + 8 * k][tx] = base[(size_t)(r0 + ty + 8 * k) * Hh + c0 + tx];
        __syncthreads();
#pragma unroll
        for (int k = 0; k < 4; ++k) {
            int h = c0 + ty + 8 * k;
            int n = (((h >> 4) * 2 + fam) << 4) + (h & 15);
            dst[(size_t)n * Dd + r0 + tx] = f2bf(tile[tx][ty + 8 * k]);
        }
    } else {
        const float* base = (sl < 8) ? w2 + (size_t)sl * Dd * Hh : sw2;
        ushort* dst = w2t + (size_t)sl * Dd * Hh;
        int r0 = blockIdx.x * 32, c0 = blockIdx.y * 32;   // r: hidden, c: dim
#pragma unroll
        for (int k = 0; k < 4; ++k)
            tile[ty + 8 * k][tx] = base[(size_t)(r0 + ty + 8 * k) * Dd + c0 + tx];
        __syncthreads();
#pragma unroll
        for (int k = 0; k < 4; ++k)
            dst[(size_t)(c0 + ty + 8 * k) * Hh + r0 + tx] = f2bf(tile[tx][ty + 8 * k]);
    }
}

// ---------- router: 32 tokens/block, LDS-aggregated atomics; also emits xb + slot map ----------
__global__ __launch_bounds__(256) void router_kernel(const float* __restrict__ x,
                                                     const float* __restrict__ gw,
                                                     const float* __restrict__ bias,
                                                     int* __restrict__ cnt,     // padded: cnt[e*32]
                                                     int* __restrict__ tok,
                                                     int* __restrict__ slotp,
                                                     float* __restrict__ pg,
                                                     ushort* __restrict__ xb) {
    __shared__ int le[64];
    __shared__ float lg[64];
    __shared__ int lpos[64];
    __shared__ int lcnt[8];
    __shared__ int gbase[8];
    int tid = threadIdx.x, lane = tid & 63, wave = tid >> 6;
    if (tid < 8) lcnt[tid] = 0;
    __syncthreads();
    int t0 = blockIdx.x * 32 + wave * 8;
    for (int it = 0; it < 8; ++it) {
        int t = t0 + it;
        const float4* xr = (const float4*)(x + (size_t)t * Dd);
        float4 xa = xr[lane * 2], xc = xr[lane * 2 + 1];
        ushort4 o1, o2;
        o1.x = f2bf(xa.x); o1.y = f2bf(xa.y); o1.z = f2bf(xa.z); o1.w = f2bf(xa.w);
        o2.x = f2bf(xc.x); o2.y = f2bf(xc.y); o2.z = f2bf(xc.z); o2.w = f2bf(xc.w);
        *(ushort4*)(xb + (size_t)t * Dd + lane * 8) = o1;
        *(ushort4*)(xb + (size_t)t * Dd + lane * 8 + 4) = o2;
        float sc[8];
#pragma unroll
        for (int e = 0; e < 8; ++e) {
            const float4* gr = (const float4*)(gw + (size_t)e * Dd);
            float4 ga = gr[lane * 2], gc = gr[lane * 2 + 1];
            float s = xa.x * ga.x + xa.y * ga.y + xa.z * ga.z + xa.w * ga.w
                    + xc.x * gc.x + xc.y * gc.y + xc.z * gc.z + xc.w * gc.w;
#pragma unroll
            for (int o = 32; o > 0; o >>= 1) s += __shfl_xor(s, o);
            sc[e] = s;
        }
        if (lane == 0) {
            float b0 = -1e30f; int i0 = 0;
#pragma unroll
            for (int e = 0; e < 8; ++e) { float bv = sc[e] + bias[e]; if (bv > b0) { b0 = bv; i0 = e; } }
            float b1v = -1e30f; int i1 = (i0 == 0) ? 1 : 0;
#pragma unroll
            for (int e = 0; e < 8; ++e) if (e != i0) { float bv = sc[e] + bias[e]; if (bv > b1v) { b1v = bv; i1 = e; } }
            float v0 = -1e30f; int k0i = 0;
#pragma unroll
            for (int e = 0; e < 8; ++e) if (sc[e] > v0) { v0 = sc[e]; k0i = e; }
            float v1 = -1e30f;
#pragma unroll
            for (int e = 0; e < 8; ++e) if (e != k0i && sc[e] > v1) v1 = sc[e];
            float p0 = 1.f / (1.f + __expf(-v0));
            float p1 = 1.f / (1.f + __expf(-v1));
            float inv = 1.f / (p0 + p1);
            int ai = (wave * 8 + it) * 2;
            le[ai] = i0;     lg[ai] = p0 * inv;
            le[ai + 1] = i1; lg[ai + 1] = p1 * inv;
        }
    }
    __syncthreads();
    if (tid < 64) lpos[tid] = atomicAdd(&lcnt[le[tid]], 1);
    __syncthreads();
    if (tid < 8) gbase[tid] = atomicAdd(&cnt[tid * 32], lcnt[tid]);
    __syncthreads();
    if (tid < 64) {
        int e = le[tid];
        int dst = gbase[e] + lpos[tid];
        int t = blockIdx.x * 32 + (tid >> 1);
        tok[(size_t)e * Tn + dst] = t;
        slotp[t * 2 + (tid & 1)] = (e << 16) | dst;
        pg[t * 2 + (tid & 1)] = lg[tid];
    }
}

// ---------- scan ----------
__global__ void scan_kernel(const int* cnt, int* off, int* cntc) {
    if (threadIdx.x == 0 && blockIdx.x == 0) {
        int s = 0;
        for (int e = 0; e < 8; ++e) { int c = cnt[e * 32]; cntc[e] = c; off[e] = s; s += c; }
        off[8] = s;
        cntc[8] = Tn;
    }
}

// ---------- stage1: plain GEMM vs interleaved w13 (N=2048), in-lane silu pairing ----------
// grid (64, 16, 9): x=row-block (pins XCD), y=n-block(128 interleaved cols = 64 hidden).
__global__ __launch_bounds__(256, 2) void stage1_kernel(
        const ushort* __restrict__ xb, const ushort* __restrict__ w13t,
        const int* __restrict__ tok, const int* __restrict__ cntc,
        const int* __restrict__ off, ushort* __restrict__ Hbuf) {
    int e = blockIdx.z;
    int cn = cntc[e];
    int m0 = blockIdx.x * 128;
    if (m0 >= cn) return;
    int n0 = blockIdx.y * 128;
    const ushort* we = w13t + (size_t)e * 2 * Hh * Dd;

    __shared__ ushort As[128 * 64];
    __shared__ ushort Bs[128 * 64];
    __shared__ int toks[128];

    int tid = threadIdx.x;
    if (tid < 128) {
        int slot = m0 + tid;
        int sl = slot < cn ? slot : cn - 1;
        toks[tid] = (e == 8) ? sl : tok[(size_t)e * Tn + sl];
    }
    __syncthreads();

    int lane = tid & 63, wave = tid >> 6;
    int wm = (wave & 1) * 64, wn = (wave >> 1) * 64;
    int col15 = lane & 15, quad = lane >> 4;
    int lr = lane >> 3;                 // row within 8-row chunk (staging)
    int lcx = ((lane & 7) ^ lr) * 8;    // swizzled logical k-offset (shorts)

    f32x4 acc[4][4];
#pragma unroll
    for (int a = 0; a < 4; ++a)
#pragma unroll
        for (int b = 0; b < 4; ++b) acc[a][b] = (f32x4){0.f, 0.f, 0.f, 0.f};

    for (int kb = 0; kb < Dd; kb += 64) {
#pragma unroll
        for (int i = 0; i < 4; ++i) {
            int cid = wave * 4 + i;
            const ushort* g = xb + (size_t)toks[cid * 8 + lr] * Dd + kb + lcx;
            __builtin_amdgcn_global_load_lds((const AS1 void*)g, (AS3 void*)(As + cid * 512), 16, 0, 0);
        }
#pragma unroll
        for (int i = 0; i < 4; ++i) {
            int cid = wave * 4 + i;
            const ushort* g = we + (size_t)(n0 + cid * 8 + lr) * Dd + kb + lcx;
            __builtin_amdgcn_global_load_lds((const AS1 void*)g, (AS3 void*)(Bs + cid * 512), 16, 0, 0);
        }
        __syncthreads();
#pragma unroll
        for (int ks = 0; ks < 2; ++ks) {
            int px = ((ks * 4 + quad) ^ (col15 & 7)) * 8;   // swizzled k-offset (shorts)
            short8 a[4], b[4];
#pragma unroll
            for (int mi = 0; mi < 4; ++mi)
                a[mi] = *(const short8*)&As[(wm + mi * 16 + col15) * 64 + px];
#pragma unroll
            for (int ni = 0; ni < 4; ++ni)
                b[ni] = *(const short8*)&Bs[(wn + ni * 16 + col15) * 64 + px];
#pragma unroll
            for (int mi = 0; mi < 4; ++mi)
#pragma unroll
                for (int ni = 0; ni < 4; ++ni)
                    acc[mi][ni] = __builtin_amdgcn_mfma_f32_16x16x32_bf16(a[mi], b[ni], acc[mi][ni], 0, 0, 0);
        }
        __syncthreads();
    }

    int oe = off[e];
    int hbase = (n0 + wn) >> 1;         // cols ni={0,1} -> h block 0, ni={2,3} -> h block 1
#pragma unroll
    for (int mi = 0; mi < 4; ++mi)
#pragma unroll
        for (int r = 0; r < 4; ++r) {
            int slot = m0 + wm + mi * 16 + quad * 4 + r;   // C layout: row = quad*4+reg
            if (slot < cn) {
                size_t rowb = (size_t)(oe + slot) * Hh;
#pragma unroll
                for (int np = 0; np < 2; ++np) {
                    float h1 = acc[mi][np * 2][r], h3 = acc[mi][np * 2 + 1][r];
                    float s = h1 / (1.f + __expf(-h1));
                    Hbuf[rowb + hbase + np * 16 + col15] = f2bf(s * h3);
                }
            }
        }
}

// ---------- stage2: Yc[slot] = Hrow @ W2, tile 128x128, BK=64 ----------
// grid (64, 4, 9): x=row-block (pins XCD), y=n-block(128 cols).
__global__ __launch_bounds__(256, 3) void stage2_kernel(
        const ushort* __restrict__ Hbuf, const ushort* __restrict__ w2t,
        const int* __restrict__ cntc, const int* __restrict__ off,
        ushort* __restrict__ Yc) {
    int e = blockIdx.z;
    int cn = cntc[e];
    int m0 = blockIdx.x * 128;
    if (m0 >= cn) return;
    int n0 = blockIdx.y * 128;
    int oe = off[e];
    const ushort* w2e = w2t + (size_t)e * Dd * Hh;

    __shared__ ushort As[128 * 64];
    __shared__ ushort Bs[128 * 64];

    int tid = threadIdx.x;
    int lane = tid & 63, wave = tid >> 6;
    int wm = (wave & 1) * 64, wn = (wave >> 1) * 64;
    int col15 = lane & 15, quad = lane >> 4;
    int lr = lane >> 3;
    int lcx = ((lane & 7) ^ lr) * 8;

    f32x4 acc[4][4];
#pragma unroll
    for (int a = 0; a < 4; ++a)
#pragma unroll
        for (int b = 0; b < 4; ++b) acc[a][b] = (f32x4){0.f, 0.f, 0.f, 0.f};

    for (int kb = 0; kb < Hh; kb += 64) {
#pragma unroll
        for (int i = 0; i < 4; ++i) {
            int cid = wave * 4 + i;
            const ushort* g = Hbuf + (size_t)(oe + m0 + cid * 8 + lr) * Hh + kb + lcx;
            __builtin_amdgcn_global_load_lds((const AS1 void*)g, (AS3 void*)(As + cid * 512), 16, 0, 0);
        }
#pragma unroll
        for (int i = 0; i < 4; ++i) {
            int cid = wave * 4 + i;
            const ushort* g = w2e + (size_t)(n0 + cid * 8 + lr) * Hh + kb + lcx;
            __builtin_amdgcn_global_load_lds((const AS1 void*)g, (AS3 void*)(Bs + cid * 512), 16, 0, 0);
        }
        __syncthreads();
#pragma unroll
        for (int ks = 0; ks < 2; ++ks) {
            int px = ((ks * 4 + quad) ^ (col15 & 7)) * 8;
            short8 a[4], b[4];
#pragma unroll
            for (int mi = 0; mi < 4; ++mi)
                a[mi] = *(const short8*)&As[(wm + mi * 16 + col15) * 64 + px];
#pragma unroll
            for (int ni = 0; ni < 4; ++ni)
                b[ni] = *(const short8*)&Bs[(wn + ni * 16 + col15) * 64 + px];
#pragma unroll
            for (int mi = 0; mi < 4; ++mi)
#pragma unroll
                for (int ni = 0; ni < 4; ++ni)
                    acc[mi][ni] = __builtin_amdgcn_mfma_f32_16x16x32_bf16(a[mi], b[ni], acc[mi][ni], 0, 0, 0);
        }
        __syncthreads();
    }

#pragma unroll
    for (int mi = 0; mi < 4; ++mi)
#pragma unroll
        for (int r = 0; r < 4; ++r) {
            int slot = m0 + wm + mi * 16 + quad * 4 + r;
            if (slot < cn) {
                size_t rowb = (size_t)(oe + slot) * Dd;
#pragma unroll
                for (int ni = 0; ni < 4; ++ni)
                    Yc[rowb + n0 + wn + ni * 16 + col15] = f2bf(acc[mi][ni][r]);
            }
        }
}

// ---------- combine: out[t] = g0*Yc[s0] + g1*Yc[s1] + Yc[shared+t] ----------
__global__ __launch_bounds__(256) void combine_kernel(const ushort* __restrict__ Yc,
        const int* __restrict__ slotp, const float* __restrict__ pg,
        const int* __restrict__ off, float* __restrict__ out) {
    int g = blockIdx.x * 256 + threadIdx.x;
    int t = g >> 6;
    int c = (g & 63) * 8;
    int p0 = slotp[t * 2], p1 = slotp[t * 2 + 1];
    float g0 = pg[t * 2], g1 = pg[t * 2 + 1];
    int s0 = off[p0 >> 16] + (p0 & 0xffff);
    int s1 = off[p1 >> 16] + (p1 & 0xffff);
    int s2 = off[8] + t;
    short8 a = *(const short8*)(Yc + (size_t)s0 * Dd + c);
    short8 b = *(const short8*)(Yc + (size_t)s1 * Dd + c);
    short8 d = *(const short8*)(Yc + (size_t)s2 * Dd + c);
    float o[8];
#pragma unroll
    for (int i = 0; i < 8; ++i)
        o[i] = g0 * bf2f(a[i]) + g1 * bf2f(b[i]) + bf2f(d[i]);
    float* dst = out + (size_t)t * Dd + c;
    *(float4*)dst = (float4){o[0], o[1], o[2], o[3]};
    *(float4*)(dst + 4) = (float4){o[4], o[5], o[6], o[7]};
}

extern "C" void kernel_launch(void* const* d_in, const int* in_sizes, int n_in,
                              void* d_out, int out_size, void* d_ws, size_t ws_size,
                              hipStream_t stream) {
    (void)in_sizes; (void)n_in; (void)out_size; (void)ws_size;
    const float* x    = (const float*)d_in[0];
    const float* gw   = (const float*)d_in[1];
    const float* bias = (const float*)d_in[2];
    const float* w1   = (const float*)d_in[3];
    const float* w3   = (const float*)d_in[4];
    const float* w2   = (const float*)d_in[5];
    const float* sw1  = (const float*)d_in[6];
    const float* sw3  = (const float*)d_in[7];
    const float* sw2  = (const float*)d_in[8];
    float* out = (float*)d_out;

    char* ws = (char*)d_ws;
    ushort* xb    = (ushort*)(ws + OFF_XB);
    ushort* w13t  = (ushort*)(ws + OFF_W13T);
    ushort* w2t   = (ushort*)(ws + OFF_W2T);
    ushort* Hbuf  = (ushort*)(ws + OFF_HBUF);
    ushort* Yc    = (ushort*)(ws + OFF_YC);
    int*    tok   = (int*)(ws + OFF_TOK);
    int*    slotp = (int*)(ws + OFF_SLOTP);
    float*  pg    = (float*)(ws + OFF_PG);
    int*    cnt   = (int*)(ws + OFF_CNT);
    int*    off   = (int*)(ws + OFF_OFFS);
    int*    cntc  = off + 16;

    hipMemsetAsync(cnt, 0, 1024, stream);

    trans_kernel<<<dim3(32, 16, 27), 256, 0, stream>>>(w1, sw1, w3, sw3, w2, sw2, w13t, w2t);
    router_kernel<<<256, 256, 0, stream>>>(x, gw, bias, cnt, tok, slotp, pg, xb);
    scan_kernel<<<1, 64, 0, stream>>>(cnt, off, cntc);

    stage1_kernel<<<dim3(64, 16, NEx), 256, 0, stream>>>(xb, w13t, tok, cntc, off, Hbuf);
    stage2_kernel<<<dim3(64, Dd / 128, NEx), 256, 0, stream>>>(Hbuf, w2t, cntc, off, Yc);
    combine_kernel<<<2048, 256, 0, stream>>>(Yc, slotp, pg, off, out);
}